// Round 7
// baseline (690.088 us; speedup 1.0000x reference)
//
#include <hip/hip_runtime.h>
#include <hip/hip_fp16.h>

#define NLAYERS 5

struct alignas(8) H4 { __half h[4]; };

typedef _Float16 half2_t __attribute__((ext_vector_type(2)));

#if defined(__has_builtin)
#if __has_builtin(__builtin_amdgcn_fdot2)
#define HAS_FDOT2 1
#endif
#endif

// ---------------- setup kernels ----------------
// one thread per edge; 4-way split counters deg4[s*N+d] (s = e&3) to cut
// atomic address/line contention 4x; rank unique within (d, s) bucket.
__global__ void k_rank(const int* __restrict__ ei, int E, int* __restrict__ deg4,
                       int* __restrict__ rank, const int* __restrict__ batch, int N,
                       int* __restrict__ cnt) {
    int i = blockIdx.x * blockDim.x + threadIdx.x;
    if (i < E) {
        int s = ei[i], d = ei[E + i];
        rank[i] = (s != d) ? atomicAdd(&deg4[(i & 3) * N + d], 1) : -1;
    }
    if (i < N) atomicAdd(&cnt[batch[i]], 1);
}

// combine sub-counters: deg[d] = sum, subofs[d] = packed exclusive byte offsets
__global__ void k_sub(const int* __restrict__ deg4, int N, int* __restrict__ deg,
                      unsigned int* __restrict__ subofs) {
    int i = blockIdx.x * blockDim.x + threadIdx.x;
    if (i >= N) return;
    int a = deg4[i], b = deg4[N + i], c = deg4[2 * N + i], d = deg4[3 * N + i];
    deg[i] = a + b + c + d;
    unsigned int s1 = (unsigned)a, s2 = (unsigned)(a + b), s3 = (unsigned)(a + b + c);
    subofs[i] = (s1 << 8) | (s2 << 16) | (s3 << 24);  // byte 0 = 0
}

// hierarchical scan: bsum -> bscan (1 block) -> rowptr
__global__ void k_bsum(const int* __restrict__ deg, int N, int* __restrict__ bsum) {
    __shared__ int sh[256];
    int t = threadIdx.x, i = blockIdx.x * 256 + t;
    sh[t] = (i < N) ? deg[i] : 0;
    __syncthreads();
    for (int o = 128; o > 0; o >>= 1) {
        if (t < o) sh[t] += sh[t + o];
        __syncthreads();
    }
    if (t == 0) bsum[blockIdx.x] = sh[0];
}

__global__ void k_bscan(const int* __restrict__ bsum, int P, int* __restrict__ boff,
                        int* __restrict__ rowptr, int N) {
    __shared__ int sh[256];
    int t = threadIdx.x;
    int v = (t < P) ? bsum[t] : 0;
    sh[t] = v;
    __syncthreads();
    for (int o = 1; o < 256; o <<= 1) {
        int u = (t >= o) ? sh[t - o] : 0;
        __syncthreads();
        sh[t] += u;
        __syncthreads();
    }
    if (t < P) boff[t] = sh[t] - v;      // exclusive
    if (t == 255) rowptr[N] = sh[255];   // total non-self edges
}

__global__ void k_rowptr(const int* __restrict__ deg, const int* __restrict__ boff, int N,
                         int* __restrict__ rowptr) {
    __shared__ int sh[256];
    int t = threadIdx.x, i = blockIdx.x * 256 + t;
    int v = (i < N) ? deg[i] : 0;
    sh[t] = v;
    __syncthreads();
    for (int o = 1; o < 256; o <<= 1) {
        int u = (t >= o) ? sh[t - o] : 0;
        __syncthreads();
        sh[t] += u;
        __syncthreads();
    }
    int ex = sh[t] - v + boff[blockIdx.x];
    if (i < N) rowptr[i] = ex;
}

// place edges without atomics: csr_eid[rowptr[d] + subofs + rank] = e
__global__ void k_scatter2(const int* __restrict__ ei, const int* __restrict__ rank,
                           const int* __restrict__ rowptr, const unsigned int* __restrict__ subofs,
                           int E, int* __restrict__ csr_eid) {
    int e = blockIdx.x * blockDim.x + threadIdx.x;
    if (e >= E) return;
    int r = rank[e];
    if (r >= 0) {
        int d = ei[E + e];
        int off = (subofs[d] >> (8 * (e & 3))) & 255;
        csr_eid[rowptr[d] + off + r] = e;
    }
}

// gather-permute: coalesced writes of csr_src + eaPerm(f16), random reads (L2/L3-served)
__global__ void k_permute(const int* __restrict__ csr_eid, const int* __restrict__ ei,
                          const float* __restrict__ edge_attr, const int* __restrict__ EnPtr,
                          int* __restrict__ csr_src, __half* __restrict__ eaPerm, int E) {
    int En = EnPtr[0];
    int j = blockIdx.x * blockDim.x + threadIdx.x;
    if (j >= En) return;
    int eid = csr_eid[j];
    csr_src[j] = ei[eid];
    const float4* ea4 = (const float4*)(edge_attr + (size_t)eid * 16);
    float4 a = ea4[0], b = ea4[1], c = ea4[2], dd = ea4[3];
    union { __half h[8]; float4 f; } u0, u1;
    u0.h[0] = __float2half(a.x); u0.h[1] = __float2half(a.y);
    u0.h[2] = __float2half(a.z); u0.h[3] = __float2half(a.w);
    u0.h[4] = __float2half(b.x); u0.h[5] = __float2half(b.y);
    u0.h[6] = __float2half(b.z); u0.h[7] = __float2half(b.w);
    u1.h[0] = __float2half(c.x); u1.h[1] = __float2half(c.y);
    u1.h[2] = __float2half(c.z); u1.h[3] = __float2half(c.w);
    u1.h[4] = __float2half(dd.x); u1.h[5] = __float2half(dd.y);
    u1.h[6] = __float2half(dd.z); u1.h[7] = __float2half(dd.w);
    float4* out = (float4*)(eaPerm + (size_t)j * 16);
    out[0] = u0.f; out[1] = u1.f;
}

// 4x4 micro-tile GEMM; AT transposed in LDS (given stride), W row-major in LDS.
template <int STRIDE>
__device__ __forceinline__ void gemm_tile(const float* AT, const float* W, float acc[4][4], int ty, int tx) {
    #pragma unroll
    for (int i = 0; i < 4; i++)
        #pragma unroll
        for (int j = 0; j < 4; j++) acc[i][j] = 0.f;
    #pragma unroll 4
    for (int k = 0; k < 64; k++) {
        const float4 a4 = *(const float4*)(AT + k * STRIDE + ty * 4);
        const float4 b4 = *(const float4*)(W + k * 64 + tx * 4);
        float a[4] = {a4.x, a4.y, a4.z, a4.w};
        float b[4] = {b4.x, b4.y, b4.z, b4.w};
        #pragma unroll
        for (int i = 0; i < 4; i++)
            #pragma unroll
            for (int j = 0; j < 4; j++) acc[i][j] += a[i] * b[j];
    }
}

// Merged prep kernel (P/Q/R fused matrices, Wpack, layer-0 GEMMs)
__global__ void k_prep(const float* __restrict__ X,
                       const float* nn2_w1, const float* nn2_w2, const float* nn2_b2,
                       const float* nn1_w1, const float* nn1_w2, const float* nn1_b2,
                       float* P, float* pb, float* Q, float* qb, float* R, float* rb,
                       __half2* Wpack, __half* __restrict__ xW1, float* __restrict__ xA0,
                       int N) {
    __shared__ float XT[64 * 68];
    __shared__ float W[64 * 64];
    int job = blockIdx.x;
    int t = threadIdx.x;
    if (job >= 13 && job < 18) {
        int l = job - 13;
        const float* Wm = nn2_w1 + (size_t)l * 5120 + 64 * 64;
        for (int i = 0; i < 2; i++) {
            int t2 = t + i * 256;
            int p = t2 >> 6, lane = t2 & 63;
            float a = Wm[(2 * p) * 64 + lane];
            float b = Wm[(2 * p + 1) * 64 + lane];
            Wpack[l * 512 + t2] = __halves2half2(__float2half(a), __float2half(b));
        }
        return;
    }
    if (job < 13) {
        const float* left; const float* lb; const float* right; float* out; float* ob;
        if (job < 5) {
            int l = job;
            left = nn2_w2 + l * 4096; lb = nn2_b2 + l * 64; right = nn1_w1 + l * 4096;
            out = P + l * 4096; ob = pb + l * 64;
        } else if (job < 9) {
            int l = job - 5;
            left = nn1_w2 + l * 4096; lb = nn1_b2 + l * 64; right = nn2_w1 + (l + 1) * 5120;
            out = Q + l * 4096; ob = qb + l * 64;
        } else {
            int l = job - 9;
            left = nn1_w2 + l * 4096; lb = nn1_b2 + l * 64; right = nn1_w1 + (l + 1) * 4096;
            out = R + l * 4096; ob = rb + l * 64;
        }
        int r0 = (t >> 4) * 4, c0 = (t & 15) * 4;
        float acc[4][4] = {};
        for (int k = 0; k < 64; k++) {
            float b[4];
            #pragma unroll
            for (int j = 0; j < 4; j++) b[j] = right[k * 64 + c0 + j];
            #pragma unroll
            for (int i = 0; i < 4; i++) {
                float a = left[(r0 + i) * 64 + k];
                #pragma unroll
                for (int j = 0; j < 4; j++) acc[i][j] += a * b[j];
            }
        }
        for (int i = 0; i < 4; i++)
            for (int j = 0; j < 4; j++)
                out[(r0 + i) * 64 + c0 + j] = acc[i][j];
        if (t < 64) {
            float s = 0.f;
            for (int k = 0; k < 64; k++) s += lb[k] * right[k * 64 + t];
            ob[t] = s;
        }
        return;
    }
    // layer-0 node GEMMs
    int ty = t >> 4, tx = t & 15;
    int base = (job - 18) * 64;
    for (int q = 0; q < 4; q++) {
        int row = ty + q * 16;
        int gr = base + row;
        float4 v = make_float4(0.f, 0.f, 0.f, 0.f);
        if (gr < N) v = *(const float4*)(X + (size_t)gr * 64 + tx * 4);
        XT[(tx * 4 + 0) * 68 + row] = v.x;
        XT[(tx * 4 + 1) * 68 + row] = v.y;
        XT[(tx * 4 + 2) * 68 + row] = v.z;
        XT[(tx * 4 + 3) * 68 + row] = v.w;
    }
    for (int q = 0; q < 4; q++) ((float4*)W)[t + q * 256] = ((const float4*)nn2_w1)[t + q * 256];
    __syncthreads();
    float acc[4][4];
    gemm_tile<68>(XT, W, acc, ty, tx);
    for (int i = 0; i < 4; i++) {
        int gr = base + ty * 4 + i;
        if (gr < N) {
            H4 o;
            o.h[0] = __float2half(acc[i][0]); o.h[1] = __float2half(acc[i][1]);
            o.h[2] = __float2half(acc[i][2]); o.h[3] = __float2half(acc[i][3]);
            *(H4*)(xW1 + (size_t)gr * 64 + tx * 4) = o;
        }
    }
    __syncthreads();
    for (int q = 0; q < 4; q++) ((float4*)W)[t + q * 256] = ((const float4*)nn1_w1)[t + q * 256];
    __syncthreads();
    gemm_tile<68>(XT, W, acc, ty, tx);
    for (int i = 0; i < 4; i++) {
        int gr = base + ty * 4 + i;
        if (gr < N) {
            float4 o = make_float4(acc[i][0], acc[i][1], acc[i][2], acc[i][3]);
            *(float4*)(xA0 + (size_t)gr * 64 + tx * 4) = o;
        }
    }
}

// Edge phase: one wave per 4 CONSECUTIVE destination nodes (contiguous CSR span),
// lane = channel. Chunks of 16 edges; staging (srcs + ea) software-pipelined one
// chunk ahead so only the gather round is latency-exposed per chunk.
__global__ __launch_bounds__(256, 8) void k_edge(
        const int* __restrict__ rowptr, const int* __restrict__ csr_src,
        const __half* __restrict__ eaPerm, const __half* __restrict__ xW1,
        const __half2* __restrict__ Wpack, const float* __restrict__ b1m,
        float* __restrict__ Hsum, int N) {
    __shared__ __align__(16) char eaL[4][512];
    int t = threadIdx.x;
    int wave = t >> 6, lane = t & 63;
    int g0 = (blockIdx.x * 4 + wave) * 4;
    if (g0 >= N) return;
    half2_t w[8];
    const unsigned int* wp = (const unsigned int*)Wpack;
    #pragma unroll
    for (int p = 0; p < 8; p++) w[p] = __builtin_bit_cast(half2_t, wp[p * 64 + lane]);
    float b1 = b1m[lane];
    int rp = 0;
    if (lane < 5) {
        int idx = g0 + lane; if (idx > N) idx = N;
        rp = rowptr[idx];
    }
    int beg  = __builtin_amdgcn_readlane(rp, 0);
    int bnd1 = __builtin_amdgcn_readlane(rp, 1);
    int bnd2 = __builtin_amdgcn_readlane(rp, 2);
    int bnd3 = __builtin_amdgcn_readlane(rp, 3);
    int end  = __builtin_amdgcn_readlane(rp, 4);
    float acc0 = 0.f, acc1 = 0.f, acc2 = 0.f, acc3 = 0.f;
    int nc = (end - beg + 15) >> 4;
    int srcv_cur = 0, srcv_nxt = 0;
    float4 ea_cur = make_float4(0.f, 0.f, 0.f, 0.f), ea_nxt = ea_cur;
    if (nc > 0) {
        // stage chunk 0
        if (lane < 16) {
            int ii = beg + lane; if (ii >= end) ii = end - 1;
            srcv_cur = csr_src[ii];
        } else if (lane >= 32) {
            int l2 = lane - 32;
            int ii = beg + (l2 >> 1); if (ii >= end) ii = end - 1;
            ea_cur = *(const float4*)((const char*)eaPerm + ((size_t)ii << 5) + ((size_t)(l2 & 1) << 4));
        }
    }
    for (int c = 0; c < nc; c++) {
        int cbeg = beg + c * 16;
        if (c + 1 < nc) {
            // stage chunk c+1 into regs (latency hidden behind this chunk's work)
            int nbeg = cbeg + 16;
            if (lane < 16) {
                int ii = nbeg + lane; if (ii >= end) ii = end - 1;
                srcv_nxt = csr_src[ii];
            } else if (lane >= 32) {
                int l2 = lane - 32;
                int ii = nbeg + (l2 >> 1); if (ii >= end) ii = end - 1;
                ea_nxt = *(const float4*)((const char*)eaPerm + ((size_t)ii << 5) + ((size_t)(l2 & 1) << 4));
            }
        }
        // current ea regs -> LDS (loaded last iteration; vmcnt wait cheap)
        if (lane >= 32) *(float4*)(&eaL[wave][(lane - 32) << 4]) = ea_cur;
        // gathers for current chunk (srcv_cur loaded last iteration)
        __half xv[16];
        #pragma unroll
        for (int i = 0; i < 16; i++) {
            int s = __builtin_amdgcn_readlane(srcv_cur, i);
            xv[i] = xW1[(size_t)s * 64 + lane];
        }
        int m = end - cbeg; if (m > 16) m = 16;
        #pragma unroll
        for (int i = 0; i < 16; i++) {
            const half2_t* e8 = (const half2_t*)(&eaL[wave][i << 5]);
            float d = __half2float(xv[i]) + b1;
#ifdef HAS_FDOT2
            #pragma unroll
            for (int p = 0; p < 8; p++) d = __builtin_amdgcn_fdot2(e8[p], w[p], d, false);
#else
            half2_t s0 = e8[0] * w[0] + e8[1] * w[1];
            #pragma unroll
            for (int p = 2; p < 8; p += 2) s0 = e8[p] * w[p] + e8[p + 1] * w[p + 1] + s0;
            d += (float)s0[0] + (float)s0[1];
#endif
            float v = (i < m) ? fmaxf(d, 0.f) : 0.f;
            int j = cbeg + i;
            if (j < bnd1) acc0 += v;
            else if (j < bnd2) acc1 += v;
            else if (j < bnd3) acc2 += v;
            else acc3 += v;
        }
        srcv_cur = srcv_nxt;
        ea_cur = ea_nxt;
    }
    if (g0 + 0 < N) Hsum[(size_t)(g0 + 0) * 64 + lane] = acc0;
    if (g0 + 1 < N) Hsum[(size_t)(g0 + 1) * 64 + lane] = acc1;
    if (g0 + 2 < N) Hsum[(size_t)(g0 + 2) * 64 + lane] = acc2;
    if (g0 + 3 < N) Hsum[(size_t)(g0 + 3) * 64 + lane] = acc3;
}

// Node phase for layer l (64-node tiles, AT reused for HT, LDS 34 KB)
__global__ void k_node(const float* __restrict__ Hsum, const float* __restrict__ xA,
                       const int* __restrict__ deg, const int* __restrict__ batch,
                       const float* __restrict__ P, const float* __restrict__ pb,
                       const float* __restrict__ a_l, const float* __restrict__ epsp,
                       const float* __restrict__ Q, const float* __restrict__ qb,
                       __half* __restrict__ out1,
                       const float* __restrict__ R, const float* __restrict__ rb,
                       float* __restrict__ out2,
                       float* __restrict__ hpool_l, int N, int has_next) {
    __shared__ float AT[64 * 68];   // Hsum^T, later reused as HT
    __shared__ float W[64 * 64];
    int t = threadIdx.x, ty = t >> 4, tx = t & 15;
    int base = blockIdx.x * 64;
    for (int q = 0; q < 4; q++) {
        int row = ty + q * 16;
        int gr = base + row;
        float4 v = make_float4(0.f, 0.f, 0.f, 0.f);
        if (gr < N) v = *(const float4*)(Hsum + (size_t)gr * 64 + tx * 4);
        AT[(tx * 4 + 0) * 68 + row] = v.x;
        AT[(tx * 4 + 1) * 68 + row] = v.y;
        AT[(tx * 4 + 2) * 68 + row] = v.z;
        AT[(tx * 4 + 3) * 68 + row] = v.w;
    }
    for (int q = 0; q < 4; q++) ((float4*)W)[t + q * 256] = ((const float4*)P)[t + q * 256];
    __syncthreads();
    float acc[4][4];
    gemm_tile<68>(AT, W, acc, ty, tx);
    float eps1 = 1.f + epsp[0];
    float4 pbv = *(const float4*)(pb + tx * 4);
    float4 av = *(const float4*)(a_l + tx * 4);
    float h[4][4];
    int gidx[4];
    for (int i = 0; i < 4; i++) {
        int gr = base + ty * 4 + i;
        float dg = 0.f;
        float4 xa = make_float4(0.f, 0.f, 0.f, 0.f);
        if (gr < N) {
            dg = (float)deg[gr];
            xa = *(const float4*)(xA + (size_t)gr * 64 + tx * 4);
            gidx[i] = batch[gr];
        } else {
            gidx[i] = -1;
        }
        h[i][0] = fmaxf(acc[i][0] + eps1 * xa.x + dg * pbv.x + av.x, 0.f);
        h[i][1] = fmaxf(acc[i][1] + eps1 * xa.y + dg * pbv.y + av.y, 0.f);
        h[i][2] = fmaxf(acc[i][2] + eps1 * xa.z + dg * pbv.z + av.z, 0.f);
        h[i][3] = fmaxf(acc[i][3] + eps1 * xa.w + dg * pbv.w + av.w, 0.f);
    }
    #pragma unroll
    for (int j = 0; j < 4; j++) {
        int i = 0;
        while (i < 4) {
            if (gidx[i] < 0) { i++; continue; }
            int g = gidx[i];
            float s = h[i][j];
            int k2 = i + 1;
            while (k2 < 4 && gidx[k2] == g) { s += h[k2][j]; k2++; }
            atomicAdd(&hpool_l[g * 64 + tx * 4 + j], s);
            i = k2;
        }
    }
    if (has_next) {
        __syncthreads();
        for (int i = 0; i < 4; i++)
            for (int j = 0; j < 4; j++)
                AT[(tx * 4 + j) * 68 + ty * 4 + i] = h[i][j];
        for (int q = 0; q < 4; q++) ((float4*)W)[t + q * 256] = ((const float4*)Q)[t + q * 256];
        __syncthreads();
        gemm_tile<68>(AT, W, acc, ty, tx);
        float4 qbv = *(const float4*)(qb + tx * 4);
        for (int i = 0; i < 4; i++) {
            int gr = base + ty * 4 + i;
            if (gr < N) {
                H4 o;
                o.h[0] = __float2half(acc[i][0] + qbv.x);
                o.h[1] = __float2half(acc[i][1] + qbv.y);
                o.h[2] = __float2half(acc[i][2] + qbv.z);
                o.h[3] = __float2half(acc[i][3] + qbv.w);
                *(H4*)(out1 + (size_t)gr * 64 + tx * 4) = o;
            }
        }
        __syncthreads();
        for (int q = 0; q < 4; q++) ((float4*)W)[t + q * 256] = ((const float4*)R)[t + q * 256];
        __syncthreads();
        gemm_tile<68>(AT, W, acc, ty, tx);
        float4 rbv = *(const float4*)(rb + tx * 4);
        for (int i = 0; i < 4; i++) {
            int gr = base + ty * 4 + i;
            if (gr < N) {
                float4 o = make_float4(acc[i][0] + rbv.x, acc[i][1] + rbv.y,
                                       acc[i][2] + rbv.z, acc[i][3] + rbv.w);
                *(float4*)(out2 + (size_t)gr * 64 + tx * 4) = o;
            }
        }
    }
}

// fused readout: feats then final MLP
__global__ void k_pool_final(const float* __restrict__ hpool, const int* __restrict__ cnt,
                             const float* __restrict__ nn1_w2, const float* __restrict__ nn1_b2,
                             const float* __restrict__ F1, const float* __restrict__ fb1,
                             const float* __restrict__ F2, const float* __restrict__ fb2,
                             float* __restrict__ out, int G) {
    int g = blockIdx.x;
    int c = threadIdx.x; // 320
    int l = c >> 6, cc = c & 63;
    const float* hp = hpool + ((size_t)l * G + g) * 64;
    const float* B = nn1_w2 + l * 4096;
    float s = (float)cnt[g] * nn1_b2[l * 64 + cc];
    for (int k = 0; k < 64; k++) s += hp[k] * B[k * 64 + cc];
    __shared__ float sh1[320];
    __shared__ float sh2[320];
    sh1[c] = s;
    __syncthreads();
    float t2 = fb1[c];
    for (int k = 0; k < 320; k++) t2 += sh1[k] * F1[k * 320 + c];
    t2 = fmaxf(t2, 0.f);
    sh2[c] = t2 * F2[c];
    __syncthreads();
    if (c == 0) {
        float y = fb2[0];
        for (int k = 0; k < 320; k++) y += sh2[k];
        out[g] = y;
    }
}

extern "C" void kernel_launch(void* const* d_in, const int* in_sizes, int n_in,
                              void* d_out, int out_size, void* d_ws, size_t ws_size,
                              hipStream_t stream) {
    const float* x        = (const float*)d_in[0];
    const int*   ei       = (const int*)d_in[1];
    const float* edge_attr= (const float*)d_in[2];
    const int*   batch    = (const int*)d_in[3];
    const float* nn2_w1   = (const float*)d_in[4];
    const float* nn2_b1   = (const float*)d_in[5];
    const float* nn2_w2   = (const float*)d_in[6];
    const float* nn2_b2   = (const float*)d_in[7];
    const float* nn1_w1   = (const float*)d_in[8];
    const float* nn1_b1   = (const float*)d_in[9];
    const float* nn1_w2   = (const float*)d_in[10];
    const float* nn1_b2   = (const float*)d_in[11];
    const float* fin_w1   = (const float*)d_in[12];
    const float* fin_b1   = (const float*)d_in[13];
    const float* fin_w2   = (const float*)d_in[14];
    const float* fin_b2   = (const float*)d_in[15];
    const float* eps      = (const float*)d_in[16];

    int N = in_sizes[0] / 64;
    int E = in_sizes[1] / 2;
    int G = out_size;

    char* p = (char*)d_ws;
    auto alloc = [&](size_t bytes) -> char* {
        char* r = p;
        p += (bytes + 255) & ~(size_t)255;
        return r;
    };
    int*    deg4    = (int*)alloc((size_t)N * 4 * 4);
    int*    deg     = (int*)alloc((size_t)N * 4);
    unsigned int* subofs = (unsigned int*)alloc((size_t)N * 4);
    int*    cnt     = (int*)alloc((size_t)G * 4);
    int*    rowptr  = (int*)alloc((size_t)(N + 1) * 4);
    int*    rank    = (int*)alloc((size_t)E * 4);
    int*    bsum    = (int*)alloc(256 * 4);
    int*    boff    = (int*)alloc(256 * 4);
    int*    csr_eid = (int*)alloc((size_t)E * 4);
    int*    csr_src = (int*)alloc((size_t)E * 4 + 256);
    __half* eaPerm  = (__half*)alloc((size_t)E * 16 * 2 + 1024);
    __half* xW1     = (__half*)alloc((size_t)N * 64 * 2);
    float*  xA0     = (float*)alloc((size_t)N * 64 * 4);
    float*  xA1     = (float*)alloc((size_t)N * 64 * 4);
    float*  Hsum    = (float*)alloc((size_t)N * 64 * 4);
    float*  hpool   = (float*)alloc((size_t)NLAYERS * G * 64 * 4);
    float*  P       = (float*)alloc(5 * 4096 * 4);
    float*  pb      = (float*)alloc(5 * 64 * 4);
    float*  Q       = (float*)alloc(4 * 4096 * 4);
    float*  qb      = (float*)alloc(4 * 64 * 4);
    float*  R       = (float*)alloc(4 * 4096 * 4);
    float*  rb      = (float*)alloc(4 * 64 * 4);
    __half2* Wpack  = (__half2*)alloc(5 * 512 * 4);

    hipMemsetAsync(deg4, 0, (size_t)N * 4 * 4, stream);
    hipMemsetAsync(cnt, 0, (size_t)G * 4, stream);
    hipMemsetAsync(hpool, 0, (size_t)NLAYERS * G * 64 * 4, stream);

    int Pblk = (N + 255) / 256;  // <= 256
    int nb64 = (N + 63) / 64;
    int EB = (E + 255) / 256;
    k_rank<<<EB, 256, 0, stream>>>(ei, E, deg4, rank, batch, N, cnt);
    k_sub<<<Pblk, 256, 0, stream>>>(deg4, N, deg, subofs);
    k_bsum<<<Pblk, 256, 0, stream>>>(deg, N, bsum);
    k_bscan<<<1, 256, 0, stream>>>(bsum, Pblk, boff, rowptr, N);
    k_rowptr<<<Pblk, 256, 0, stream>>>(deg, boff, N, rowptr);
    k_scatter2<<<EB, 256, 0, stream>>>(ei, rank, rowptr, subofs, E, csr_eid);
    k_permute<<<EB, 256, 0, stream>>>(csr_eid, ei, edge_attr, rowptr + N, csr_src, eaPerm, E);
    k_prep<<<18 + nb64, 256, 0, stream>>>(x, nn2_w1, nn2_w2, nn2_b2, nn1_w1, nn1_w2, nn1_b2,
                                          P, pb, Q, qb, R, rb, Wpack, xW1, xA0, N);

    float* xA_cur = xA0;
    float* xA_nxt = xA1;
    int ngroups = (N + 3) / 4;           // 4 nodes per wave
    int eblocks = (ngroups + 3) / 4;     // 4 waves per block
    for (int l = 0; l < NLAYERS; l++) {
        int has_next = (l < NLAYERS - 1) ? 1 : 0;
        k_edge<<<eblocks, 256, 0, stream>>>(rowptr, csr_src, eaPerm, xW1,
                                            Wpack + l * 512, nn2_b1 + l * 64, Hsum, N);
        k_node<<<nb64, 256, 0, stream>>>(Hsum, xA_cur, deg, batch,
                                         P + l * 4096, pb + l * 64, nn1_b1 + l * 64, eps,
                                         Q + (has_next ? l : 0) * 4096, qb + (has_next ? l : 0) * 64, xW1,
                                         R + (has_next ? l : 0) * 4096, rb + (has_next ? l : 0) * 64, xA_nxt,
                                         hpool + (size_t)l * G * 64, N, has_next);
        float* tmp = xA_cur; xA_cur = xA_nxt; xA_nxt = tmp;
    }

    k_pool_final<<<G, 320, 0, stream>>>(hpool, cnt, nn1_w2, nn1_b2,
                                        fin_w1, fin_b1, fin_w2, fin_b2, (float*)d_out, G);
}

// Round 8
// 615.524 us; speedup vs baseline: 1.1211x; 1.1211x over previous
//
#include <hip/hip_runtime.h>
#include <hip/hip_fp16.h>

#define NLAYERS 5

struct alignas(8) H4 { __half h[4]; };

typedef _Float16 half2_t __attribute__((ext_vector_type(2)));

#if defined(__has_builtin)
#if __has_builtin(__builtin_amdgcn_fdot2)
#define HAS_FDOT2 1
#endif
#endif

// 4x4 micro-tile GEMM; AT transposed in LDS (given stride), W row-major in LDS.
template <int STRIDE>
__device__ __forceinline__ void gemm_tile(const float* AT, const float* W, float acc[4][4], int ty, int tx) {
    #pragma unroll
    for (int i = 0; i < 4; i++)
        #pragma unroll
        for (int j = 0; j < 4; j++) acc[i][j] = 0.f;
    #pragma unroll 4
    for (int k = 0; k < 64; k++) {
        const float4 a4 = *(const float4*)(AT + k * STRIDE + ty * 4);
        const float4 b4 = *(const float4*)(W + k * 64 + tx * 4);
        float a[4] = {a4.x, a4.y, a4.z, a4.w};
        float b[4] = {b4.x, b4.y, b4.z, b4.w};
        #pragma unroll
        for (int i = 0; i < 4; i++)
            #pragma unroll
            for (int j = 0; j < 4; j++) acc[i][j] += a[i] * b[j];
    }
}

// Fused: blocks [0,EB) = rank/hist (atomic-latency-bound, ~idle pipes);
//        blocks [EB,EB+13) = P/Q/R fused 64x64 GEMMs;
//        blocks [EB+13,EB+18) = Wpack f16;
//        blocks [EB+18,...) = layer-0 node GEMMs (VALU-heavy, hides in rank's stalls).
__global__ void k_rank_prep(const int* __restrict__ ei, int E, int* __restrict__ deg,
                            int* __restrict__ rank, const int* __restrict__ batch,
                            int* __restrict__ cnt,
                            const float* __restrict__ X,
                            const float* nn2_w1, const float* nn2_w2, const float* nn2_b2,
                            const float* nn1_w1, const float* nn1_w2, const float* nn1_b2,
                            float* P, float* pb, float* Q, float* qb, float* R, float* rb,
                            __half2* Wpack, __half* __restrict__ xW1, float* __restrict__ xA0,
                            int N, int EB) {
    __shared__ float XT[64 * 68];
    __shared__ float W[64 * 64];
    int t = threadIdx.x;
    if (blockIdx.x < EB) {
        int i = blockIdx.x * 256 + t;
        if (i < E) {
            int s = ei[i], d = ei[E + i];
            rank[i] = (s != d) ? atomicAdd(&deg[d], 1) : -1;
        }
        if (i < N) atomicAdd(&cnt[batch[i]], 1);
        return;
    }
    int job = blockIdx.x - EB;
    if (job >= 13 && job < 18) {
        int l = job - 13;
        const float* Wm = nn2_w1 + (size_t)l * 5120 + 64 * 64;
        for (int i = 0; i < 2; i++) {
            int t2 = t + i * 256;
            int p = t2 >> 6, lane = t2 & 63;
            float a = Wm[(2 * p) * 64 + lane];
            float b = Wm[(2 * p + 1) * 64 + lane];
            Wpack[l * 512 + t2] = __halves2half2(__float2half(a), __float2half(b));
        }
        return;
    }
    if (job < 13) {
        const float* left; const float* lb; const float* right; float* out; float* ob;
        if (job < 5) {
            int l = job;
            left = nn2_w2 + l * 4096; lb = nn2_b2 + l * 64; right = nn1_w1 + l * 4096;
            out = P + l * 4096; ob = pb + l * 64;
        } else if (job < 9) {
            int l = job - 5;
            left = nn1_w2 + l * 4096; lb = nn1_b2 + l * 64; right = nn2_w1 + (l + 1) * 5120;
            out = Q + l * 4096; ob = qb + l * 64;
        } else {
            int l = job - 9;
            left = nn1_w2 + l * 4096; lb = nn1_b2 + l * 64; right = nn1_w1 + (l + 1) * 4096;
            out = R + l * 4096; ob = rb + l * 64;
        }
        int r0 = (t >> 4) * 4, c0 = (t & 15) * 4;
        float acc[4][4] = {};
        for (int k = 0; k < 64; k++) {
            float b[4];
            #pragma unroll
            for (int j = 0; j < 4; j++) b[j] = right[k * 64 + c0 + j];
            #pragma unroll
            for (int i = 0; i < 4; i++) {
                float a = left[(r0 + i) * 64 + k];
                #pragma unroll
                for (int j = 0; j < 4; j++) acc[i][j] += a * b[j];
            }
        }
        for (int i = 0; i < 4; i++)
            for (int j = 0; j < 4; j++)
                out[(r0 + i) * 64 + c0 + j] = acc[i][j];
        if (t < 64) {
            float s = 0.f;
            for (int k = 0; k < 64; k++) s += lb[k] * right[k * 64 + t];
            ob[t] = s;
        }
        return;
    }
    // layer-0 node GEMMs: xW1(f16) = x@Wx0, xA0(f32) = x@A0
    int ty = t >> 4, tx = t & 15;
    int base = (job - 18) * 64;
    for (int q = 0; q < 4; q++) {
        int row = ty + q * 16;
        int gr = base + row;
        float4 v = make_float4(0.f, 0.f, 0.f, 0.f);
        if (gr < N) v = *(const float4*)(X + (size_t)gr * 64 + tx * 4);
        XT[(tx * 4 + 0) * 68 + row] = v.x;
        XT[(tx * 4 + 1) * 68 + row] = v.y;
        XT[(tx * 4 + 2) * 68 + row] = v.z;
        XT[(tx * 4 + 3) * 68 + row] = v.w;
    }
    for (int q = 0; q < 4; q++) ((float4*)W)[t + q * 256] = ((const float4*)nn2_w1)[t + q * 256];
    __syncthreads();
    float acc[4][4];
    gemm_tile<68>(XT, W, acc, ty, tx);
    for (int i = 0; i < 4; i++) {
        int gr = base + ty * 4 + i;
        if (gr < N) {
            H4 o;
            o.h[0] = __float2half(acc[i][0]); o.h[1] = __float2half(acc[i][1]);
            o.h[2] = __float2half(acc[i][2]); o.h[3] = __float2half(acc[i][3]);
            *(H4*)(xW1 + (size_t)gr * 64 + tx * 4) = o;
        }
    }
    __syncthreads();
    for (int q = 0; q < 4; q++) ((float4*)W)[t + q * 256] = ((const float4*)nn1_w1)[t + q * 256];
    __syncthreads();
    gemm_tile<68>(XT, W, acc, ty, tx);
    for (int i = 0; i < 4; i++) {
        int gr = base + ty * 4 + i;
        if (gr < N) {
            float4 o = make_float4(acc[i][0], acc[i][1], acc[i][2], acc[i][3]);
            *(float4*)(xA0 + (size_t)gr * 64 + tx * 4) = o;
        }
    }
}

// hierarchical scan: bsum -> bscan (1 block) -> rowptr
__global__ void k_bsum(const int* __restrict__ deg, int N, int* __restrict__ bsum) {
    __shared__ int sh[256];
    int t = threadIdx.x, i = blockIdx.x * 256 + t;
    sh[t] = (i < N) ? deg[i] : 0;
    __syncthreads();
    for (int o = 128; o > 0; o >>= 1) {
        if (t < o) sh[t] += sh[t + o];
        __syncthreads();
    }
    if (t == 0) bsum[blockIdx.x] = sh[0];
}

__global__ void k_bscan(const int* __restrict__ bsum, int P, int* __restrict__ boff,
                        int* __restrict__ rowptr, int N) {
    __shared__ int sh[256];
    int t = threadIdx.x;
    int v = (t < P) ? bsum[t] : 0;
    sh[t] = v;
    __syncthreads();
    for (int o = 1; o < 256; o <<= 1) {
        int u = (t >= o) ? sh[t - o] : 0;
        __syncthreads();
        sh[t] += u;
        __syncthreads();
    }
    if (t < P) boff[t] = sh[t] - v;      // exclusive
    if (t == 255) rowptr[N] = sh[255];   // total non-self edges
}

__global__ void k_rowptr(const int* __restrict__ deg, const int* __restrict__ boff, int N,
                         int* __restrict__ rowptr) {
    __shared__ int sh[256];
    int t = threadIdx.x, i = blockIdx.x * 256 + t;
    int v = (i < N) ? deg[i] : 0;
    sh[t] = v;
    __syncthreads();
    for (int o = 1; o < 256; o <<= 1) {
        int u = (t >= o) ? sh[t - o] : 0;
        __syncthreads();
        sh[t] += u;
        __syncthreads();
    }
    int ex = sh[t] - v + boff[blockIdx.x];
    if (i < N) rowptr[i] = ex;
}

// place edges without atomics: csr_eid[rowptr[d] + rank[e]] = e
__global__ void k_scatter2(const int* __restrict__ ei, const int* __restrict__ rank,
                           const int* __restrict__ rowptr, int E, int* __restrict__ csr_eid) {
    int e = blockIdx.x * blockDim.x + threadIdx.x;
    if (e >= E) return;
    int r = rank[e];
    if (r >= 0) {
        int d = ei[E + e];
        csr_eid[rowptr[d] + r] = e;
    }
}

// gather-permute: coalesced writes of csr_src + eaPerm(f16), random reads (L2/L3-served)
__global__ void k_permute(const int* __restrict__ csr_eid, const int* __restrict__ ei,
                          const float* __restrict__ edge_attr, const int* __restrict__ EnPtr,
                          int* __restrict__ csr_src, __half* __restrict__ eaPerm, int E) {
    int En = EnPtr[0];
    int j = blockIdx.x * blockDim.x + threadIdx.x;
    if (j >= En) return;
    int eid = csr_eid[j];
    csr_src[j] = ei[eid];
    const float4* ea4 = (const float4*)(edge_attr + (size_t)eid * 16);
    float4 a = ea4[0], b = ea4[1], c = ea4[2], dd = ea4[3];
    union { __half h[8]; float4 f; } u0, u1;
    u0.h[0] = __float2half(a.x); u0.h[1] = __float2half(a.y);
    u0.h[2] = __float2half(a.z); u0.h[3] = __float2half(a.w);
    u0.h[4] = __float2half(b.x); u0.h[5] = __float2half(b.y);
    u0.h[6] = __float2half(b.z); u0.h[7] = __float2half(b.w);
    u1.h[0] = __float2half(c.x); u1.h[1] = __float2half(c.y);
    u1.h[2] = __float2half(c.z); u1.h[3] = __float2half(c.w);
    u1.h[4] = __float2half(dd.x); u1.h[5] = __float2half(dd.y);
    u1.h[6] = __float2half(dd.z); u1.h[7] = __float2half(dd.w);
    float4* out = (float4*)(eaPerm + (size_t)j * 16);
    out[0] = u0.f; out[1] = u1.f;
}

// Edge phase: one wave per destination node, lane = channel. Chunk of 16 edges:
// 1 coalesced src load (readlane broadcast), 1 coalesced 512B ea load staged via
// wave-private LDS, 16 xW1 gathers issued back-to-back. (R6 version — best so far.)
__global__ __launch_bounds__(256, 8) void k_edge(
        const int* __restrict__ rowptr, const int* __restrict__ csr_src,
        const __half* __restrict__ eaPerm, const __half* __restrict__ xW1,
        const __half2* __restrict__ Wpack, const float* __restrict__ b1m,
        float* __restrict__ Hsum, int N) {
    __shared__ __align__(16) char eaL[4][16 * 32];
    int t = threadIdx.x;
    int wave = t >> 6, lane = t & 63;
    int wid = __builtin_amdgcn_readfirstlane(blockIdx.x * 4 + wave);
    if (wid >= N) return;
    half2_t w[8];
    const unsigned int* wp = (const unsigned int*)Wpack;
    #pragma unroll
    for (int p = 0; p < 8; p++) w[p] = __builtin_bit_cast(half2_t, wp[p * 64 + lane]);
    float b1 = b1m[lane];
    int beg = __builtin_amdgcn_readfirstlane(rowptr[wid]);
    int end = __builtin_amdgcn_readfirstlane(rowptr[wid + 1]);
    float acc = 0.f;
    for (int cbeg = beg; cbeg < end; cbeg += 16) {
        int m = end - cbeg; m = (m < 16) ? m : 16;
        int srcv = 0;
        if (lane < 16) {
            int ii = (lane < m) ? lane : (m - 1);
            srcv = csr_src[cbeg + ii];
        } else if (lane >= 32) {
            int l2 = lane - 32;
            int eidx = l2 >> 1;
            int ii = (eidx < m) ? eidx : (m - 1);
            float4 v = *(const float4*)((const char*)eaPerm + ((size_t)(cbeg + ii) << 5) + ((size_t)(l2 & 1) << 4));
            *(float4*)(&eaL[wave][l2 << 4]) = v;
        }
        __half xv[16];
        #pragma unroll
        for (int i = 0; i < 16; i++) {
            int s = __builtin_amdgcn_readlane(srcv, i);
            xv[i] = xW1[(size_t)s * 64 + lane];
        }
        #pragma unroll
        for (int i = 0; i < 16; i++) {
            const half2_t* e8 = (const half2_t*)(&eaL[wave][i << 5]);
            float d = __half2float(xv[i]) + b1;
#ifdef HAS_FDOT2
            #pragma unroll
            for (int p = 0; p < 8; p++) d = __builtin_amdgcn_fdot2(e8[p], w[p], d, false);
#else
            half2_t s0 = e8[0] * w[0] + e8[1] * w[1];
            #pragma unroll
            for (int p = 2; p < 8; p += 2) s0 = e8[p] * w[p] + e8[p + 1] * w[p + 1] + s0;
            d += (float)s0[0] + (float)s0[1];
#endif
            acc += (i < m) ? fmaxf(d, 0.f) : 0.f;
        }
    }
    Hsum[(size_t)wid * 64 + lane] = acc;
}

// Node phase for layer l (64-node tiles, AT reused for HT).
// Pooled readout now LDS-pre-reduced: batch is sorted, so a 64-node tile spans
// only a few graphs -> ~span*64 global atomics per block instead of ~1024.
__global__ void k_node(const float* __restrict__ Hsum, const float* __restrict__ xA,
                       const int* __restrict__ deg, const int* __restrict__ batch,
                       const float* __restrict__ P, const float* __restrict__ pb,
                       const float* __restrict__ a_l, const float* __restrict__ epsp,
                       const float* __restrict__ Q, const float* __restrict__ qb,
                       __half* __restrict__ out1,
                       const float* __restrict__ R, const float* __restrict__ rb,
                       float* __restrict__ out2,
                       float* __restrict__ hpool_l, int N, int has_next) {
    __shared__ float AT[64 * 68];   // Hsum^T, later reused as HT
    __shared__ float W[64 * 64];
    __shared__ float shp[8 * 64];   // local pool tile (up to 8 graphs)
    int t = threadIdx.x, ty = t >> 4, tx = t & 15;
    int base = blockIdx.x * 64;
    int lastn = base + 63; if (lastn > N - 1) lastn = N - 1;
    int gmin = batch[base];
    int span = batch[lastn] - gmin + 1;
    if (span <= 8) {
        for (int q = t; q < span * 64; q += 256) shp[q] = 0.f;
    }
    for (int q = 0; q < 4; q++) {
        int row = ty + q * 16;
        int gr = base + row;
        float4 v = make_float4(0.f, 0.f, 0.f, 0.f);
        if (gr < N) v = *(const float4*)(Hsum + (size_t)gr * 64 + tx * 4);
        AT[(tx * 4 + 0) * 68 + row] = v.x;
        AT[(tx * 4 + 1) * 68 + row] = v.y;
        AT[(tx * 4 + 2) * 68 + row] = v.z;
        AT[(tx * 4 + 3) * 68 + row] = v.w;
    }
    for (int q = 0; q < 4; q++) ((float4*)W)[t + q * 256] = ((const float4*)P)[t + q * 256];
    __syncthreads();
    float acc[4][4];
    gemm_tile<68>(AT, W, acc, ty, tx);
    float eps1 = 1.f + epsp[0];
    float4 pbv = *(const float4*)(pb + tx * 4);
    float4 av = *(const float4*)(a_l + tx * 4);
    float h[4][4];
    int gidx[4];
    for (int i = 0; i < 4; i++) {
        int gr = base + ty * 4 + i;
        float dg = 0.f;
        float4 xa = make_float4(0.f, 0.f, 0.f, 0.f);
        if (gr < N) {
            dg = (float)deg[gr];
            xa = *(const float4*)(xA + (size_t)gr * 64 + tx * 4);
            gidx[i] = batch[gr];
        } else {
            gidx[i] = -1;
        }
        h[i][0] = fmaxf(acc[i][0] + eps1 * xa.x + dg * pbv.x + av.x, 0.f);
        h[i][1] = fmaxf(acc[i][1] + eps1 * xa.y + dg * pbv.y + av.y, 0.f);
        h[i][2] = fmaxf(acc[i][2] + eps1 * xa.z + dg * pbv.z + av.z, 0.f);
        h[i][3] = fmaxf(acc[i][3] + eps1 * xa.w + dg * pbv.w + av.w, 0.f);
    }
    if (span <= 8) {
        #pragma unroll
        for (int j = 0; j < 4; j++) {
            int i = 0;
            while (i < 4) {
                if (gidx[i] < 0) { i++; continue; }
                int g = gidx[i];
                float s = h[i][j];
                int k2 = i + 1;
                while (k2 < 4 && gidx[k2] == g) { s += h[k2][j]; k2++; }
                atomicAdd(&shp[(g - gmin) * 64 + tx * 4 + j], s);
                i = k2;
            }
        }
        __syncthreads();
        for (int q = t; q < span * 64; q += 256) {
            float v = shp[q];
            if (v != 0.f) atomicAdd(&hpool_l[(gmin + (q >> 6)) * 64 + (q & 63)], v);
        }
    } else {
        #pragma unroll
        for (int j = 0; j < 4; j++) {
            int i = 0;
            while (i < 4) {
                if (gidx[i] < 0) { i++; continue; }
                int g = gidx[i];
                float s = h[i][j];
                int k2 = i + 1;
                while (k2 < 4 && gidx[k2] == g) { s += h[k2][j]; k2++; }
                atomicAdd(&hpool_l[g * 64 + tx * 4 + j], s);
                i = k2;
            }
        }
    }
    if (has_next) {
        __syncthreads();  // all reads of AT done — safe to overwrite with HT
        for (int i = 0; i < 4; i++)
            for (int j = 0; j < 4; j++)
                AT[(tx * 4 + j) * 68 + ty * 4 + i] = h[i][j];
        for (int q = 0; q < 4; q++) ((float4*)W)[t + q * 256] = ((const float4*)Q)[t + q * 256];
        __syncthreads();
        gemm_tile<68>(AT, W, acc, ty, tx);
        float4 qbv = *(const float4*)(qb + tx * 4);
        for (int i = 0; i < 4; i++) {
            int gr = base + ty * 4 + i;
            if (gr < N) {
                H4 o;
                o.h[0] = __float2half(acc[i][0] + qbv.x);
                o.h[1] = __float2half(acc[i][1] + qbv.y);
                o.h[2] = __float2half(acc[i][2] + qbv.z);
                o.h[3] = __float2half(acc[i][3] + qbv.w);
                *(H4*)(out1 + (size_t)gr * 64 + tx * 4) = o;
            }
        }
        __syncthreads();
        for (int q = 0; q < 4; q++) ((float4*)W)[t + q * 256] = ((const float4*)R)[t + q * 256];
        __syncthreads();
        gemm_tile<68>(AT, W, acc, ty, tx);
        float4 rbv = *(const float4*)(rb + tx * 4);
        for (int i = 0; i < 4; i++) {
            int gr = base + ty * 4 + i;
            if (gr < N) {
                float4 o = make_float4(acc[i][0] + rbv.x, acc[i][1] + rbv.y,
                                       acc[i][2] + rbv.z, acc[i][3] + rbv.w);
                *(float4*)(out2 + (size_t)gr * 64 + tx * 4) = o;
            }
        }
    }
}

// fused readout: feats then final MLP
__global__ void k_pool_final(const float* __restrict__ hpool, const int* __restrict__ cnt,
                             const float* __restrict__ nn1_w2, const float* __restrict__ nn1_b2,
                             const float* __restrict__ F1, const float* __restrict__ fb1,
                             const float* __restrict__ F2, const float* __restrict__ fb2,
                             float* __restrict__ out, int G) {
    int g = blockIdx.x;
    int c = threadIdx.x; // 320
    int l = c >> 6, cc = c & 63;
    const float* hp = hpool + ((size_t)l * G + g) * 64;
    const float* B = nn1_w2 + l * 4096;
    float s = (float)cnt[g] * nn1_b2[l * 64 + cc];
    for (int k = 0; k < 64; k++) s += hp[k] * B[k * 64 + cc];
    __shared__ float sh1[320];
    __shared__ float sh2[320];
    sh1[c] = s;
    __syncthreads();
    float t2 = fb1[c];
    for (int k = 0; k < 320; k++) t2 += sh1[k] * F1[k * 320 + c];
    t2 = fmaxf(t2, 0.f);
    sh2[c] = t2 * F2[c];
    __syncthreads();
    if (c == 0) {
        float y = fb2[0];
        for (int k = 0; k < 320; k++) y += sh2[k];
        out[g] = y;
    }
}

extern "C" void kernel_launch(void* const* d_in, const int* in_sizes, int n_in,
                              void* d_out, int out_size, void* d_ws, size_t ws_size,
                              hipStream_t stream) {
    const float* x        = (const float*)d_in[0];
    const int*   ei       = (const int*)d_in[1];
    const float* edge_attr= (const float*)d_in[2];
    const int*   batch    = (const int*)d_in[3];
    const float* nn2_w1   = (const float*)d_in[4];
    const float* nn2_b1   = (const float*)d_in[5];
    const float* nn2_w2   = (const float*)d_in[6];
    const float* nn2_b2   = (const float*)d_in[7];
    const float* nn1_w1   = (const float*)d_in[8];
    const float* nn1_b1   = (const float*)d_in[9];
    const float* nn1_w2   = (const float*)d_in[10];
    const float* nn1_b2   = (const float*)d_in[11];
    const float* fin_w1   = (const float*)d_in[12];
    const float* fin_b1   = (const float*)d_in[13];
    const float* fin_w2   = (const float*)d_in[14];
    const float* fin_b2   = (const float*)d_in[15];
    const float* eps      = (const float*)d_in[16];

    int N = in_sizes[0] / 64;
    int E = in_sizes[1] / 2;
    int G = out_size;

    char* p = (char*)d_ws;
    auto alloc = [&](size_t bytes) -> char* {
        char* r = p;
        p += (bytes + 255) & ~(size_t)255;
        return r;
    };
    int*    deg     = (int*)alloc((size_t)N * 4);
    int*    cnt     = (int*)alloc((size_t)G * 4);
    int*    rowptr  = (int*)alloc((size_t)(N + 1) * 4);
    int*    rank    = (int*)alloc((size_t)E * 4);
    int*    bsum    = (int*)alloc(256 * 4);
    int*    boff    = (int*)alloc(256 * 4);
    int*    csr_eid = (int*)alloc((size_t)E * 4);
    int*    csr_src = (int*)alloc((size_t)E * 4 + 256);
    __half* eaPerm  = (__half*)alloc((size_t)E * 16 * 2 + 1024);
    __half* xW1     = (__half*)alloc((size_t)N * 64 * 2);
    float*  xA0     = (float*)alloc((size_t)N * 64 * 4);
    float*  xA1     = (float*)alloc((size_t)N * 64 * 4);
    float*  Hsum    = (float*)alloc((size_t)N * 64 * 4);
    float*  hpool   = (float*)alloc((size_t)NLAYERS * G * 64 * 4);
    float*  P       = (float*)alloc(5 * 4096 * 4);
    float*  pb      = (float*)alloc(5 * 64 * 4);
    float*  Q       = (float*)alloc(4 * 4096 * 4);
    float*  qb      = (float*)alloc(4 * 64 * 4);
    float*  R       = (float*)alloc(4 * 4096 * 4);
    float*  rb      = (float*)alloc(4 * 64 * 4);
    __half2* Wpack  = (__half2*)alloc(5 * 512 * 4);

    hipMemsetAsync(deg, 0, (size_t)N * 4, stream);
    hipMemsetAsync(cnt, 0, (size_t)G * 4, stream);
    hipMemsetAsync(hpool, 0, (size_t)NLAYERS * G * 64 * 4, stream);

    int Pblk = (N + 255) / 256;  // <= 256
    int nb64 = (N + 63) / 64;
    int EB = (E + 255) / 256;
    k_rank_prep<<<EB + 18 + nb64, 256, 0, stream>>>(ei, E, deg, rank, batch, cnt,
                                                    x, nn2_w1, nn2_w2, nn2_b2, nn1_w1, nn1_w2, nn1_b2,
                                                    P, pb, Q, qb, R, rb, Wpack, xW1, xA0, N, EB);
    k_bsum<<<Pblk, 256, 0, stream>>>(deg, N, bsum);
    k_bscan<<<1, 256, 0, stream>>>(bsum, Pblk, boff, rowptr, N);
    k_rowptr<<<Pblk, 256, 0, stream>>>(deg, boff, N, rowptr);
    k_scatter2<<<EB, 256, 0, stream>>>(ei, rank, rowptr, E, csr_eid);
    k_permute<<<EB, 256, 0, stream>>>(csr_eid, ei, edge_attr, rowptr + N, csr_src, eaPerm, E);

    float* xA_cur = xA0;
    float* xA_nxt = xA1;
    int eblocks = (N + 3) / 4; // 4 waves/block, one wave per node
    for (int l = 0; l < NLAYERS; l++) {
        int has_next = (l < NLAYERS - 1) ? 1 : 0;
        k_edge<<<eblocks, 256, 0, stream>>>(rowptr, csr_src, eaPerm, xW1,
                                            Wpack + l * 512, nn2_b1 + l * 64, Hsum, N);
        k_node<<<nb64, 256, 0, stream>>>(Hsum, xA_cur, deg, batch,
                                         P + l * 4096, pb + l * 64, nn1_b1 + l * 64, eps,
                                         Q + (has_next ? l : 0) * 4096, qb + (has_next ? l : 0) * 64, xW1,
                                         R + (has_next ? l : 0) * 4096, rb + (has_next ? l : 0) * 64, xA_nxt,
                                         hpool + (size_t)l * G * 64, N, has_next);
        float* tmp = xA_cur; xA_cur = xA_nxt; xA_nxt = tmp;
    }

    k_pool_final<<<G, 320, 0, stream>>>(hpool, cnt, nn1_w2, nn1_b2,
                                        fin_w1, fin_b1, fin_w2, fin_b2, (float*)d_out, G);
}